// Round 2
// baseline (98.779 us; speedup 1.0000x reference)
//
#include <hip/hip_runtime.h>
#include <hip/hip_bf16.h>
#include <math.h>

// SemiCRF dense span scores, MI355X gfx950.
// Structure: per block (8 i's): stage x -> local prefix sums c1/c2 in LDS ->
// per-wave 16-row agg tiles (bf16, xor-swizzled) -> mfma_f32_16x16x32_bf16
// vs register-resident W1 frags -> f32 epilogue (relu, W2 dot, shfl reduce).
// K-layout hedge: A-fill and B-fill use the SAME (lane,elem)->k map, so any
// HW K-permutation cancels; only C/D layout (HW-verified) is relied upon.

typedef __attribute__((ext_vector_type(4))) float f32x4;
typedef __attribute__((ext_vector_type(8))) short bf16x8;
typedef __attribute__((ext_vector_type(2))) unsigned int u32x2;

#define L_SEQ 8192
#define F_DIM 26
#define SEG 100
#define HID 64
#define BI 8
#define REG_ROWS (BI + SEG - 1)            /* 107 x-rows per block */
#define C_ROWS (REG_ROWS + 1)              /* 108 prefix entries   */
#define C_STRIDE 28                        /* f32 per c-row (16B-multiple) */
#define C_BYTES (C_ROWS * C_STRIDE * 4)    /* 12096 */
#define XS_OFF (2 * C_BYTES)               /* 24192 */
#define XS_ELEMS (REG_ROWS * F_DIM)        /* 2782  */
#define SMEM_BYTES (XS_OFF + XS_ELEMS * 4) /* 35320 */

__device__ __forceinline__ unsigned short f2bf(float v) {
    unsigned u = __builtin_bit_cast(unsigned, v);
    u += 0x7FFFu + ((u >> 16) & 1u);   // round-to-nearest-even
    return (unsigned short)(u >> 16);
}
__device__ __forceinline__ unsigned pk(unsigned short a, unsigned short b) {
    return (unsigned)a | ((unsigned)b << 16);
}

__global__ __launch_bounds__(256, 4)
void semicrf_kernel(const float* __restrict__ x, const float* __restrict__ W1,
                    const float* __restrict__ b1, const float* __restrict__ W2,
                    const float* __restrict__ b2, float* __restrict__ out) {
    __shared__ __align__(16) char smem[SMEM_BYTES];
    float* c1 = (float*)smem;
    float* c2 = (float*)(smem + C_BYTES);
    float* xs = (float*)(smem + XS_OFF);   // aliased by agg tiles after scan

    const int tid = threadIdx.x;
    const int lane = tid & 63;
    const int wave = tid >> 6;
    const int i0 = blockIdx.x * BI;

    // ---- stage x rows [i0, i0+107) into LDS, zero-padded past L ----
    for (int e = tid; e < XS_ELEMS; e += 256) {
        int gi = i0 * F_DIM + e;
        xs[e] = (gi < L_SEQ * F_DIM) ? x[gi] : 0.0f;
    }

    // ---- per-lane register fragments of W1 (bf16) + b1/W2/b2 (f32) ----
    // agg column map: [0..25]=mean_f, [26..31]=0, [32..57]=var_(c-32),
    //                 [58,59]=0, [60]=len, [61]=loglen, [62,63]=0
    const int r = lane & 15;   // tile row (A) / output col n (B,D)
    const int q = lane >> 4;   // k-group
    bf16x8 bfrag[2][4];
#pragma unroll
    for (int s = 0; s < 2; ++s) {
#pragma unroll
        for (int t = 0; t < 4; ++t) {
            bf16x8 v;
#pragma unroll
            for (int j = 0; j < 8; ++j) {
                int c = s * 32 + q * 8 + j;    // SAME k-map as A-frag reads
                int wr;
                if (c < 26) wr = c;
                else if (c >= 32 && c < 58) wr = c - 6;
                else if (c == 60) wr = 52;
                else if (c == 61) wr = 53;
                else wr = -1;
                float wv = (wr >= 0) ? W1[wr * HID + (t * 16 + r)] : 0.0f;
                v[j] = (short)f2bf(wv);
            }
            bfrag[s][t] = v;
        }
    }
    float b1v[4], w2v[4];
#pragma unroll
    for (int t = 0; t < 4; ++t) {
        b1v[t] = b1[t * 16 + r];
        w2v[t] = W2[t * 16 + r];
    }
    const float b2v = b2[0];

    __syncthreads();

    // ---- local prefix sums (28 scan lanes of wave 0; cols 26,27 == 0) ----
    if (tid < C_STRIDE) {
        const int f = tid;
        float s1 = 0.0f, s2 = 0.0f;
        c1[f] = 0.0f;
        c2[f] = 0.0f;
#pragma unroll 4
        for (int rr = 0; rr < REG_ROWS; ++rr) {
            float xv = (f < F_DIM) ? xs[rr * F_DIM + f] : 0.0f;
            s1 += xv;
            s2 = fmaf(xv, xv, s2);
            c1[(rr + 1) * C_STRIDE + f] = s1;
            c2[(rr + 1) * C_STRIDE + f] = s2;
        }
    }
    __syncthreads();

    // ---- main loop: 56 tiles (8 i x 7 l-chunks), wave-private agg buffers ----
    char* aggw = smem + XS_OFF + wave * 2048;  // 16 rows x 128 B, xor-swizzled
    char* rowp = aggw + r * 128;
    const int sz = (r & 7) << 4;               // bank-conflict xor swizzle

    for (int tt = wave; tt < 56; tt += 4) {
        const int bi = tt & 7;
        const int lc = tt >> 3;
        const int i = i0 + bi;
        const int l0 = lc * 16;
        const int l_seg = l0 + 1 + r;                 // this lane's tile row
        const float inv_l = 1.0f / (float)l_seg;
        const int cj = min(bi + l_seg, REG_ROWS);     // clamp junk rows (l>100)
        const int ci = bi;

        // fence: prior tile's frag reads complete before overwriting
        asm volatile("s_waitcnt lgkmcnt(0)" ::: "memory");

        {   // quad f0 = 4q  (mean cols f0.., var cols 32+f0..)
            const int f0 = 4 * q;
            f32x4 c1j = *(const f32x4*)(c1 + cj * C_STRIDE + f0);
            f32x4 c1i = *(const f32x4*)(c1 + ci * C_STRIDE + f0);
            f32x4 c2j = *(const f32x4*)(c2 + cj * C_STRIDE + f0);
            f32x4 c2i = *(const f32x4*)(c2 + ci * C_STRIDE + f0);
            f32x4 mean = (c1j - c1i) * inv_l;
            f32x4 var  = (c2j - c2i) * inv_l - mean * mean;
            u32x2 mp, vp;
            mp.x = pk(f2bf(mean.x), f2bf(mean.y));
            mp.y = pk(f2bf(mean.z), f2bf(mean.w));
            vp.x = pk(f2bf(var.x), f2bf(var.y));
            vp.y = pk(f2bf(var.z), f2bf(var.w));
            *(u32x2*)(rowp + ((2 * f0) ^ sz)) = mp;
            *(u32x2*)(rowp + ((64 + 2 * f0) ^ sz)) = vp;
        }
        if (q < 3) {   // quad f0 = 16+4q (covers f up to 27; c cols 26,27 are 0)
            const int f0 = 16 + 4 * q;
            f32x4 c1j = *(const f32x4*)(c1 + cj * C_STRIDE + f0);
            f32x4 c1i = *(const f32x4*)(c1 + ci * C_STRIDE + f0);
            f32x4 c2j = *(const f32x4*)(c2 + cj * C_STRIDE + f0);
            f32x4 c2i = *(const f32x4*)(c2 + ci * C_STRIDE + f0);
            f32x4 mean = (c1j - c1i) * inv_l;
            f32x4 var  = (c2j - c2i) * inv_l - mean * mean;
            u32x2 mp, vp;
            mp.x = pk(f2bf(mean.x), f2bf(mean.y));
            mp.y = pk(f2bf(mean.z), f2bf(mean.w));
            vp.x = pk(f2bf(var.x), f2bf(var.y));
            vp.y = pk(f2bf(var.z), f2bf(var.w));
            *(u32x2*)(rowp + ((2 * f0) ^ sz)) = mp;
            *(u32x2*)(rowp + ((64 + 2 * f0) ^ sz)) = vp;
        } else {       // pad cols 28..31, len/loglen at 60/61, pad 62,63
            *(unsigned*)(rowp + (56 ^ sz)) = 0u;
            *(unsigned*)(rowp + (60 ^ sz)) = 0u;
            float lf = (float)l_seg;
            unsigned lp = pk(f2bf(lf * 0.002f),
                             f2bf(logf(lf + 1e-6f) * (1.0f / 6.0f)));
            *(unsigned*)(rowp + (120 ^ sz)) = lp;
            *(unsigned*)(rowp + (124 ^ sz)) = 0u;
        }

        // fence: builds visible before cross-lane frag reads
        asm volatile("s_waitcnt lgkmcnt(0)" ::: "memory");

        bf16x8 a0 = *(const bf16x8*)(rowp + ((q * 16) ^ sz));        // k 0..31
        bf16x8 a1 = *(const bf16x8*)(rowp + ((64 + q * 16) ^ sz));   // k 32..63

        f32x4 acc0 = {0.f, 0.f, 0.f, 0.f};
        f32x4 acc1 = {0.f, 0.f, 0.f, 0.f};
        f32x4 acc2 = {0.f, 0.f, 0.f, 0.f};
        f32x4 acc3 = {0.f, 0.f, 0.f, 0.f};
        acc0 = __builtin_amdgcn_mfma_f32_16x16x32_bf16(a0, bfrag[0][0], acc0, 0, 0, 0);
        acc1 = __builtin_amdgcn_mfma_f32_16x16x32_bf16(a0, bfrag[0][1], acc1, 0, 0, 0);
        acc2 = __builtin_amdgcn_mfma_f32_16x16x32_bf16(a0, bfrag[0][2], acc2, 0, 0, 0);
        acc3 = __builtin_amdgcn_mfma_f32_16x16x32_bf16(a0, bfrag[0][3], acc3, 0, 0, 0);
        acc0 = __builtin_amdgcn_mfma_f32_16x16x32_bf16(a1, bfrag[1][0], acc0, 0, 0, 0);
        acc1 = __builtin_amdgcn_mfma_f32_16x16x32_bf16(a1, bfrag[1][1], acc1, 0, 0, 0);
        acc2 = __builtin_amdgcn_mfma_f32_16x16x32_bf16(a1, bfrag[1][2], acc2, 0, 0, 0);
        acc3 = __builtin_amdgcn_mfma_f32_16x16x32_bf16(a1, bfrag[1][3], acc3, 0, 0, 0);

        // epilogue in f32: relu(h+b1) . W2, summed over in-lane n-tiles then
        // over the 16 lanes sharing q (D layout: row=(l>>4)*4+reg, col=l&15)
        float p0 = 0.f, p1 = 0.f, p2 = 0.f, p3 = 0.f;
#define EPI(ACC, T)                                            \
        p0 = fmaf(fmaxf(ACC[0] + b1v[T], 0.f), w2v[T], p0);    \
        p1 = fmaf(fmaxf(ACC[1] + b1v[T], 0.f), w2v[T], p1);    \
        p2 = fmaf(fmaxf(ACC[2] + b1v[T], 0.f), w2v[T], p2);    \
        p3 = fmaf(fmaxf(ACC[3] + b1v[T], 0.f), w2v[T], p3);
        EPI(acc0, 0) EPI(acc1, 1) EPI(acc2, 2) EPI(acc3, 3)
#undef EPI
#pragma unroll
        for (int off = 1; off < 16; off <<= 1) {
            p0 += __shfl_xor(p0, off);
            p1 += __shfl_xor(p1, off);
            p2 += __shfl_xor(p2, off);
            p3 += __shfl_xor(p3, off);
        }
        if (r == 0) {
            const int lbase = l0 + q * 4;          // output column base (l-1)
            if (lbase <= SEG - 4) {
                f32x4 vv;
                vv.x = (i + lbase + 1 <= L_SEQ) ? p0 + b2v : 0.0f;
                vv.y = (i + lbase + 2 <= L_SEQ) ? p1 + b2v : 0.0f;
                vv.z = (i + lbase + 3 <= L_SEQ) ? p2 + b2v : 0.0f;
                vv.w = (i + lbase + 4 <= L_SEQ) ? p3 + b2v : 0.0f;
                *(f32x4*)(out + i * SEG + lbase) = vv;
            }
        }
    }
}

extern "C" void kernel_launch(void* const* d_in, const int* in_sizes, int n_in,
                              void* d_out, int out_size, void* d_ws, size_t ws_size,
                              hipStream_t stream) {
    const float* x  = (const float*)d_in[0];
    const float* W1 = (const float*)d_in[1];
    const float* b1 = (const float*)d_in[2];
    const float* W2 = (const float*)d_in[3];
    const float* b2 = (const float*)d_in[4];
    float* out = (float*)d_out;
    semicrf_kernel<<<dim3(L_SEQ / BI), dim3(256), 0, stream>>>(x, W1, b1, W2, b2, out);
}

// Round 3
// 88.077 us; speedup vs baseline: 1.1215x; 1.1215x over previous
//
#include <hip/hip_runtime.h>
#include <hip/hip_bf16.h>
#include <math.h>

// SemiCRF dense span scores, MI355X gfx950.  Round 3 structure:
// per block (8 i's): stage x -> local prefix sums c1/c2 in LDS -> per-wave
// 16-row agg tiles (bf16, xor-swizzled) -> mfma(W1^T, agg) (operand-swapped:
// D[row=hid, col=seg_row]) -> f32 epilogue: relu dot W2 in-lane (16 terms),
// 2-shuffle reduce over q, all 16 lanes store.
// VALU cuts vs round 2: v_cvt_pk_bf16_f32 pack, 1/l + len/loglen LUTs,
// compiler-only fences (no runtime lgkmcnt(0); DS pipe is in-order per wave).

typedef __attribute__((ext_vector_type(4))) float f32x4;
typedef __attribute__((ext_vector_type(8))) short bf16x8;
typedef __attribute__((ext_vector_type(2))) unsigned int u32x2;

#define L_SEQ 8192
#define F_DIM 26
#define SEG 100
#define HID 64
#define BI 8
#define REG_ROWS (BI + SEG - 1)            /* 107 x-rows per block */
#define C_ROWS (REG_ROWS + 1)              /* 108 prefix entries   */
#define C_STRIDE 28                        /* f32 per c-row (16B-multiple) */
#define C_BYTES (C_ROWS * C_STRIDE * 4)    /* 12096 */
#define LUT_OFF (2 * C_BYTES)              /* 24192 */
#define LUT_N 112                          /* covers junk l up to 112 */
#define XS_OFF (LUT_OFF + LUT_N * 8)       /* 25088 */
#define XS_ELEMS (REG_ROWS * F_DIM)        /* 2782  */
#define SMEM_BYTES (XS_OFF + XS_ELEMS * 4) /* 36216 (4 blocks/CU) */

__device__ __forceinline__ unsigned short f2bf(float v) {   // setup-only path
    unsigned u = __builtin_bit_cast(unsigned, v);
    u += 0x7FFFu + ((u >> 16) & 1u);   // round-to-nearest-even
    return (unsigned short)(u >> 16);
}
__device__ __forceinline__ unsigned pk(unsigned short a, unsigned short b) {
    return (unsigned)a | ((unsigned)b << 16);
}
__device__ __forceinline__ unsigned cvtpk(float lo, float hi) {  // hot path
    unsigned r;
    asm("v_cvt_pk_bf16_f32 %0, %1, %2" : "=v"(r) : "v"(lo), "v"(hi));
    return r;
}

__global__ __launch_bounds__(256, 4)
void semicrf_kernel(const float* __restrict__ x, const float* __restrict__ W1,
                    const float* __restrict__ b1, const float* __restrict__ W2,
                    const float* __restrict__ b2, float* __restrict__ out) {
    __shared__ __align__(16) char smem[SMEM_BYTES];
    float*    c1    = (float*)smem;
    float*    c2    = (float*)(smem + C_BYTES);
    float*    invlt = (float*)(smem + LUT_OFF);
    unsigned* lenlt = (unsigned*)(smem + LUT_OFF + LUT_N * 4);
    float*    xs    = (float*)(smem + XS_OFF);   // aliased by agg tiles

    const int tid = threadIdx.x;
    const int lane = tid & 63;
    const int wave = tid >> 6;
    const int i0 = blockIdx.x * BI;

    // ---- stage x rows [i0, i0+107) into LDS, zero-padded past L ----
    for (int e = tid; e < XS_ELEMS; e += 256) {
        int gi = i0 * F_DIM + e;
        xs[e] = (gi < L_SEQ * F_DIM) ? x[gi] : 0.0f;
    }
    // ---- 1/l and len/loglen LUTs (once per block) ----
    if (tid < LUT_N) {
        float lf = (float)(tid + 1);
        invlt[tid] = 1.0f / lf;
        lenlt[tid] = pk(f2bf(lf * 0.002f), f2bf(logf(lf + 1e-6f) * (1.0f / 6.0f)));
    }

    // ---- per-lane W1^T fragments (A-operand), W2 quads, b1 quads ----
    // agg K map: [0..25]=mean_f, [26..31]=0, [32..57]=var_(c-32),
    //            [58,59]=0, [60]=len, [61]=loglen, [62,63]=0
    const int r = lane & 15;   // A row (hid low) / B col (seg_row) / D col
    const int q = lane >> 4;   // k-group; D rows q*4+g
    bf16x8 bfrag[2][4];
#pragma unroll
    for (int s = 0; s < 2; ++s) {
#pragma unroll
        for (int t = 0; t < 4; ++t) {
            bf16x8 v;
#pragma unroll
            for (int j = 0; j < 8; ++j) {
                int c = s * 32 + q * 8 + j;    // SAME k-map as B-frag reads
                int wr;
                if (c < 26) wr = c;
                else if (c >= 32 && c < 58) wr = c - 6;
                else if (c == 60) wr = 52;
                else if (c == 61) wr = 53;
                else wr = -1;
                float wv = (wr >= 0) ? W1[wr * HID + (t * 16 + r)] : 0.0f;
                v[j] = (short)f2bf(wv);
            }
            bfrag[s][t] = v;
        }
    }
    // D[row=hid t*16+q*4+g][col=seg_row r] -> this lane needs b1/W2 at q*4+g
    f32x4 b1v[4], w2v[4];
#pragma unroll
    for (int t = 0; t < 4; ++t) {
        b1v[t] = *(const f32x4*)(b1 + t * 16 + q * 4);
        w2v[t] = *(const f32x4*)(W2 + t * 16 + q * 4);
    }
    const float b2v = b2[0];

    __syncthreads();

    // ---- local prefix sums (28 scan lanes of wave 0; cols 26,27 == 0) ----
    if (tid < C_STRIDE) {
        const int f = tid;
        float s1 = 0.0f, s2 = 0.0f;
        c1[f] = 0.0f;
        c2[f] = 0.0f;
#pragma unroll 4
        for (int rr = 0; rr < REG_ROWS; ++rr) {
            float xv = (f < F_DIM) ? xs[rr * F_DIM + f] : 0.0f;
            s1 += xv;
            s2 = fmaf(xv, xv, s2);
            c1[(rr + 1) * C_STRIDE + f] = s1;
            c2[(rr + 1) * C_STRIDE + f] = s2;
        }
    }
    __syncthreads();

    // ---- main loop: 14 tiles/wave (7 l-chunks x 2 i's), wave-private agg ----
    char* rowp = smem + XS_OFF + wave * 2048 + r * 128;
    const int sz = (r & 7) << 4;               // bank-conflict xor swizzle

    for (int lc = 0; lc < 7; ++lc) {
        const int l0 = lc * 16;
        const int l_seg = l0 + 1 + r;          // this lane's seg length
        const float inv_l = invlt[l_seg - 1];
        const unsigned lp = lenlt[l_seg - 1];
#pragma unroll
        for (int bih = 0; bih < 2; ++bih) {
            const int bi = wave + 4 * bih;
            const int i = i0 + bi;
            const int cj = min(bi + l_seg, REG_ROWS);  // clamp junk rows
            const int ci = bi;

            // compiler fence: prior tile's frag reads ordered before overwrite
            // (DS pipe is in-order per wave; no runtime waitcnt needed)
            asm volatile("" ::: "memory");

            {   // quad f0 = 4q (all lanes; q==3 covers f 12..15)
                const int f0 = 4 * q;
                f32x4 c1j = *(const f32x4*)(c1 + cj * C_STRIDE + f0);
                f32x4 c1i = *(const f32x4*)(c1 + ci * C_STRIDE + f0);
                f32x4 c2j = *(const f32x4*)(c2 + cj * C_STRIDE + f0);
                f32x4 c2i = *(const f32x4*)(c2 + ci * C_STRIDE + f0);
                f32x4 mean = (c1j - c1i) * inv_l;
                f32x4 var  = (c2j - c2i) * inv_l - mean * mean;
                u32x2 mp, vp;
                mp.x = cvtpk(mean[0], mean[1]);
                mp.y = cvtpk(mean[2], mean[3]);
                vp.x = cvtpk(var[0], var[1]);
                vp.y = cvtpk(var[2], var[3]);
                *(u32x2*)(rowp + ((2 * f0) ^ sz)) = mp;
                *(u32x2*)(rowp + ((64 + 2 * f0) ^ sz)) = vp;
            }
            if (q < 3) {   // quad f0 = 16+4q (f 16..27; c cols 26,27 are 0)
                const int f0 = 16 + 4 * q;
                f32x4 c1j = *(const f32x4*)(c1 + cj * C_STRIDE + f0);
                f32x4 c1i = *(const f32x4*)(c1 + ci * C_STRIDE + f0);
                f32x4 c2j = *(const f32x4*)(c2 + cj * C_STRIDE + f0);
                f32x4 c2i = *(const f32x4*)(c2 + ci * C_STRIDE + f0);
                f32x4 mean = (c1j - c1i) * inv_l;
                f32x4 var  = (c2j - c2i) * inv_l - mean * mean;
                u32x2 mp, vp;
                mp.x = cvtpk(mean[0], mean[1]);
                mp.y = cvtpk(mean[2], mean[3]);
                vp.x = cvtpk(var[0], var[1]);
                vp.y = cvtpk(var[2], var[3]);
                *(u32x2*)(rowp + ((2 * f0) ^ sz)) = mp;
                *(u32x2*)(rowp + ((64 + 2 * f0) ^ sz)) = vp;
            } else {       // pad cols 28..31, len/loglen at 60/61, pad 62,63
                *(unsigned*)(rowp + (56 ^ sz)) = 0u;
                *(unsigned*)(rowp + (60 ^ sz)) = 0u;
                *(unsigned*)(rowp + (120 ^ sz)) = lp;
                *(unsigned*)(rowp + (124 ^ sz)) = 0u;
            }

            // compiler fence: builds ordered before cross-lane frag reads
            asm volatile("" ::: "memory");

            bf16x8 a0 = *(const bf16x8*)(rowp + ((q * 16) ^ sz));       // k 0..31
            bf16x8 a1 = *(const bf16x8*)(rowp + ((64 + q * 16) ^ sz));  // k 32..63

            f32x4 acc0 = b1v[0], acc1 = b1v[1], acc2 = b1v[2], acc3 = b1v[3];
            acc0 = __builtin_amdgcn_mfma_f32_16x16x32_bf16(bfrag[0][0], a0, acc0, 0, 0, 0);
            acc1 = __builtin_amdgcn_mfma_f32_16x16x32_bf16(bfrag[0][1], a0, acc1, 0, 0, 0);
            acc2 = __builtin_amdgcn_mfma_f32_16x16x32_bf16(bfrag[0][2], a0, acc2, 0, 0, 0);
            acc3 = __builtin_amdgcn_mfma_f32_16x16x32_bf16(bfrag[0][3], a0, acc3, 0, 0, 0);
            acc0 = __builtin_amdgcn_mfma_f32_16x16x32_bf16(bfrag[1][0], a1, acc0, 0, 0, 0);
            acc1 = __builtin_amdgcn_mfma_f32_16x16x32_bf16(bfrag[1][1], a1, acc1, 0, 0, 0);
            acc2 = __builtin_amdgcn_mfma_f32_16x16x32_bf16(bfrag[1][2], a1, acc2, 0, 0, 0);
            acc3 = __builtin_amdgcn_mfma_f32_16x16x32_bf16(bfrag[1][3], a1, acc3, 0, 0, 0);

            // epilogue: p = sum_t sum_g relu(h) * w2, 4 partials then tree
            float p0 = 0.f, p1 = 0.f, p2 = 0.f, p3 = 0.f;
#define EPI(ACC, PT, T)                                             \
            PT = fmaf(fmaxf(ACC[0], 0.f), w2v[T][0], PT);           \
            PT = fmaf(fmaxf(ACC[1], 0.f), w2v[T][1], PT);           \
            PT = fmaf(fmaxf(ACC[2], 0.f), w2v[T][2], PT);           \
            PT = fmaf(fmaxf(ACC[3], 0.f), w2v[T][3], PT);
            EPI(acc0, p0, 0) EPI(acc1, p1, 1) EPI(acc2, p2, 2) EPI(acc3, p3, 3)
#undef EPI
            float p = (p0 + p1) + (p2 + p3);
            p += __shfl_xor(p, 16);            // reduce over q (4 k-groups)
            p += __shfl_xor(p, 32);

            if (lane < 16) {                   // one lane per seg_row
                const int l = l0 + 1 + r;
                if (l <= SEG)
                    out[i * SEG + (l - 1)] = (i + l <= L_SEQ) ? p + b2v : 0.0f;
            }
        }
    }
}

extern "C" void kernel_launch(void* const* d_in, const int* in_sizes, int n_in,
                              void* d_out, int out_size, void* d_ws, size_t ws_size,
                              hipStream_t stream) {
    const float* x  = (const float*)d_in[0];
    const float* W1 = (const float*)d_in[1];
    const float* b1 = (const float*)d_in[2];
    const float* W2 = (const float*)d_in[3];
    const float* b2 = (const float*)d_in[4];
    float* out = (float*)d_out;
    semicrf_kernel<<<dim3(L_SEQ / BI), dim3(256), 0, stream>>>(x, W1, b1, W2, b2, out);
}